// Round 11
// baseline (97.171 us; speedup 1.0000x reference)
//
#include <hip/hip_runtime.h>
#include <stdint.h>

#define B_TOT 2048
#define H_DIM 4096
#define R_DIM 64
#define NA_DIM 64
#define GS 16
#define X_ELEMS (B_TOT*H_DIM)        // 8388608
#define W_ELEMS (B_TOT)              // 2048
#define A_ELEMS (NA_DIM*H_DIM*R_DIM) // 16777216

// Block (adapter a, k-slice ks): 4 waves, k in [ks*KS, (ks+1)*KS).
// No A staging: A rows stream from global, perfectly coalesced
// (1 KB/wave per 4-k iter), depth-2 register prefetch. Only x is staged in
// LDS ([s][k], padded). Compute is barrier-free; per-group epilogue does a
// 2-step shfl_xor k-reduce + cross-wave LDS reduce, then writes f32 partial
// slice ks to ws. NS is 16 or 8 ONLY (NS=1 would need 262 KB LDS).
template<int NS>
__global__ __launch_bounds__(256, 4)
void k_lora_stream(const float* __restrict__ x, const int* __restrict__ wids,
                   const float* __restrict__ A, float* __restrict__ part) {
  constexpr int KS = H_DIM / NS;     // 256 (NS=16) / 512 (NS=8)
  constexpr int XPAD = KS + 4;
  constexpr int RSN = 4 * 16 * 68;   // 4352 f32 reduce scratch (aliases XT)
  constexpr int POOLN = (GS * XPAD > RSN ? GS * XPAD : RSN);
  __shared__ __align__(16) float POOL[POOLN];
  __shared__ uint16_t sbin[B_TOT];   // 4 KB ordered sample list
  __shared__ int sn;

  const int bx = blockIdx.x;
  const int a = bx / NS, ks = bx % NS;
  const int t = threadIdx.x;
  const int w = t >> 6, l = t & 63;

  // ---- wave 0: ballot-scan wids -> ordered bin list (deterministic) ----
  if (w == 0) {
    int v[32];
#pragma unroll
    for (int i = 0; i < 32; ++i) v[i] = wids[i * 64 + l];
    int cnt = 0;
#pragma unroll
    for (int i = 0; i < 32; ++i) {
      bool hit = (v[i] == a);
      unsigned long long m = __ballot(hit);
      if (hit) sbin[cnt + __popcll(m & ((1ull << l) - 1ull))] = (uint16_t)(i * 64 + l);
      cnt += __popcll(m);
    }
    if (l == 0) sn = cnt;
  }
  __syncthreads();
  const int n = sn;
  if (n == 0) return;

  const int rq = l & 15;             // r-quad
  const int lg = l >> 4;             // k-sub in 4-row A load
  const int s_st = t >> 4, q_st = t & 15;   // staging roles
  const int wkb = w * (KS / 4);      // wave k-base within slice
  constexpr int NIT = KS / 16;       // 4-k iters per wave

  const float* Aslice = A + ((size_t)a * H_DIM + (size_t)ks * KS) * R_DIM;
  const float* Agl = Aslice + (size_t)wkb * R_DIM + l * 4;  // lane A stream base

  for (int g = 0; g * GS < n; ++g) {
    const int base = g * GS;
    __syncthreads();   // POOL free (prev group's final reads done)

    // ---- stage x tile [s][k]: 16 samples x KS, coalesced 16B x KS/64 ----
    {
      int sidx = base + s_st; if (sidx > n - 1) sidx = n - 1;
      const float* xr = x + (size_t)sbin[sidx] * H_DIM + (size_t)ks * KS + q_st * (KS / 16);
      float* xd = POOL + s_st * XPAD + q_st * (KS / 16);
#pragma unroll
      for (int i = 0; i < KS / 64; ++i)
        *(float4*)(xd + i * 4) = *(const float4*)(xr + i * 4);
    }
    __syncthreads();   // XT ready

    // ---- barrier-free compute: stream A, depth-2 prefetch ----
    float acc[GS][4];
#pragma unroll
    for (int s = 0; s < GS; ++s)
#pragma unroll
      for (int c = 0; c < 4; ++c) acc[s][c] = 0.f;

    float4 a_cur = *(const float4*)(Agl);
    float4 a_nxt = *(const float4*)(Agl + 256);
    const float* xbase = POOL + wkb + lg;
#pragma unroll 2
    for (int it = 0; it < NIT; ++it) {
      const int pfi = (it + 2 < NIT) ? (it + 2) : 0;
      float4 a_pf = *(const float4*)(Agl + (size_t)pfi * 256);
      const float* xb = xbase + it * 4;
#pragma unroll
      for (int s = 0; s < GS; ++s) {
        float xs = xb[s * XPAD];   // ds_read_b32, imm offset s*XPAD*4
        acc[s][0] += xs * a_cur.x; acc[s][1] += xs * a_cur.y;
        acc[s][2] += xs * a_cur.z; acc[s][3] += xs * a_cur.w;
      }
      a_cur = a_nxt; a_nxt = a_pf;
    }

    // ---- intra-wave k-reduce (over lg) via 2-step butterfly ----
#pragma unroll
    for (int s = 0; s < GS; ++s)
#pragma unroll
      for (int c = 0; c < 4; ++c) {
        float v = acc[s][c];
        v += __shfl_xor(v, 16);
        v += __shfl_xor(v, 32);
        acc[s][c] = v;
      }

    __syncthreads();   // all XT reads done -> POOL reusable as RS
    // RS[w][16][68]: lane (lg,rq) writes s = lg*4..lg*4+3 (dup values over lg)
    {
      float* rs = POOL + w * 1088;
#pragma unroll
      for (int j = 0; j < 4; ++j) {
        int s = lg * 4 + j;
        *(float4*)(rs + s * 68 + rq * 4) =
            make_float4(acc[s][0], acc[s][1], acc[s][2], acc[s][3]);
      }
    }
    __syncthreads();   // RS ready

    // ---- final: thread (fs, frq) sums 4 waves, writes partial slice ----
    {
      int fs = t >> 4, frq = t & 15;
      int sidx = base + fs;
      if (sidx < n) {
        float4 s0 = *(const float4*)(POOL + 0 * 1088 + fs * 68 + frq * 4);
        float4 s1 = *(const float4*)(POOL + 1 * 1088 + fs * 68 + frq * 4);
        float4 s2 = *(const float4*)(POOL + 2 * 1088 + fs * 68 + frq * 4);
        float4 s3 = *(const float4*)(POOL + 3 * 1088 + fs * 68 + frq * 4);
        float4 r = make_float4(s0.x + s1.x + s2.x + s3.x,
                               s0.y + s1.y + s2.y + s3.y,
                               s0.z + s1.z + s2.z + s3.z,
                               s0.w + s1.w + s2.w + s3.w);
        *(float4*)&part[(size_t)ks * (B_TOT * R_DIM) +
                        (size_t)sbin[sidx] * R_DIM + frq * 4] = r;
      }
    }
  }
}

template<int NS>
__global__ __launch_bounds__(256)
void k_reduceN(const float* __restrict__ part, float* __restrict__ out) {
  int t = blockIdx.x * 256 + threadIdx.x;   // 32768 threads, one float4 each
  size_t o = (size_t)t * 4;
  float v0 = 0.f, v1 = 0.f, v2 = 0.f, v3 = 0.f;
#pragma unroll
  for (int p = 0; p < NS; ++p) {
    float4 q = *(const float4*)&part[(size_t)p * (B_TOT * R_DIM) + o];
    v0 += q.x; v1 += q.y; v2 += q.z; v3 += q.w;
  }
  *(float4*)&out[o] = make_float4(v0, v1, v2, v3);
}

// No-workspace fallback (proven-correct round-6 naive kernel).
__global__ __launch_bounds__(256)
void k_naive_f32(const float* __restrict__ x, const int* __restrict__ wids,
                 const float* __restrict__ A, float* __restrict__ out) {
  __shared__ float red[256];
  const int b = blockIdx.x;
  const int t = threadIdx.x;
  const int r = t & 63;
  const int q = t >> 6;
  const int a = wids[b];
  const float* xrow = x + (size_t)b * H_DIM;
  const float* Aad  = A + (size_t)a * H_DIM * R_DIM + r;
  float acc = 0.f;
  const int h0 = q * (H_DIM / 4), h1 = h0 + (H_DIM / 4);
  for (int h = h0; h < h1; ++h) acc += xrow[h] * Aad[(size_t)h * R_DIM];
  red[t] = acc;
  __syncthreads();
  if (t < 64) {
    out[(size_t)b * R_DIM + t] = red[t] + red[t + 64] + red[t + 128] + red[t + 192];
  }
}

extern "C" void kernel_launch(void* const* d_in, const int* in_sizes, int n_in,
                              void* d_out, int out_size, void* d_ws, size_t ws_size,
                              hipStream_t stream) {
  // Identify inputs by element count — robust to any ordering.
  const void* px = nullptr; const void* pw = nullptr; const void* pa = nullptr;
  for (int i = 0; i < n_in; ++i) {
    if (in_sizes[i] == X_ELEMS) px = d_in[i];
    else if (in_sizes[i] == W_ELEMS) pw = d_in[i];
    else if (in_sizes[i] == A_ELEMS) pa = d_in[i];
  }
  if (!px || !pw || !pa) { px = d_in[0]; pw = d_in[1]; pa = d_in[2]; }

  const float* x    = (const float*)px;
  const int*   wids = (const int*)pw;
  const float* A    = (const float*)pa;
  float* out = (float*)d_out;
  (void)out_size;

  const size_t need16 = (size_t)16 * B_TOT * R_DIM * sizeof(float);  // 8 MB
  const size_t need8  = (size_t)8  * B_TOT * R_DIM * sizeof(float);  // 4 MB (proven fits)
  float* part = (float*)d_ws;
  if (ws_size >= need16) {
    k_lora_stream<16><<<dim3(NA_DIM * 16), dim3(256), 0, stream>>>(x, wids, A, part);
    k_reduceN<16><<<dim3(128), dim3(256), 0, stream>>>(part, out);
  } else if (ws_size >= need8) {
    k_lora_stream<8><<<dim3(NA_DIM * 8), dim3(256), 0, stream>>>(x, wids, A, part);
    k_reduceN<8><<<dim3(128), dim3(256), 0, stream>>>(part, out);
  } else {
    k_naive_f32<<<dim3(B_TOT), dim3(256), 0, stream>>>(x, wids, A, out);
  }
}